// Round 9
// baseline (467.824 us; speedup 1.0000x reference)
//
#include <hip/hip_runtime.h>

typedef unsigned short u16;
typedef __attribute__((ext_vector_type(8))) short short8;
typedef __attribute__((ext_vector_type(8))) unsigned short u16x8;
typedef __attribute__((ext_vector_type(4))) float f32x4;

#define GLOAD16(SRC, DST) __builtin_amdgcn_global_load_lds( \
    (const __attribute__((address_space(1))) void*)(SRC),   \
    (__attribute__((address_space(3))) void*)(DST), 16, 0, 0)

// LDS chunk swizzle: spreads a column of 16B chunks across bank-groups.
#define SWZ(BKv, r) ((BKv) == 32 ? (((r) >> 1) & 3) : ((r) & 7))

// 0.125 * log2(e): folds softmax scale + exp->exp2 conversion into Q projection
#define QSCALE 0.18033688011112042f

__device__ __forceinline__ u16 f2bf(float f) {
  union { float f; unsigned u; } v; v.f = f;
  unsigned r = v.u + 0x7fffu + ((v.u >> 16) & 1u);
  return (u16)(r >> 16);
}
__device__ __forceinline__ float bf2f(u16 h) {
  union { unsigned u; float f; } v; v.u = ((unsigned)h) << 16;
  return v.f;
}

// ---------------- fused weights f32 -> bf16 convert (6 segments, contiguous dst) ----
__global__ __launch_bounds__(256) void wcvt_kernel(const float* __restrict__ s0,
                                                   const float* __restrict__ s1,
                                                   const float* __restrict__ s2,
                                                   const float* __restrict__ s3,
                                                   const float* __restrict__ s4,
                                                   const float* __restrict__ s5,
                                                   u16* __restrict__ dst) {
  long i = ((long)blockIdx.x * 256 + threadIdx.x) * 4;
  const float* src; long off;
  if (i < 3145728)        { src = s0; off = 0; }
  else if (i < 4194304)   { src = s1; off = 3145728; }
  else if (i < 7340032)   { src = s2; off = 4194304; }
  else if (i < 8388608)   { src = s3; off = 7340032; }
  else if (i < 12582912)  { src = s4; off = 8388608; }
  else                    { src = s5; off = 12582912; }
  float4 v = *(const float4*)(src + (i - off));
  ushort4 o; o.x = f2bf(v.x); o.y = f2bf(v.y); o.z = f2bf(v.z); o.w = f2bf(v.w);
  *(ushort4*)(dst + i) = o;
}

// ---------------- pos embed (revolution-domain v_sin/v_cos) + optional raw cast ----
__global__ __launch_bounds__(256) void pos_embed_kernel(const float* __restrict__ x,
                                                        const float* __restrict__ pos,
                                                        u16* __restrict__ out,
                                                        u16* __restrict__ out2,
                                                        u16* __restrict__ raw) {
  int m = blockIdx.x;
  int tid = threadIdx.x;
  float p = pos[m];
  long base = ((long)m << 10);
  int j = tid * 4;
  float4 xv = *(const float4*)(x + base + j);
  const float inv = 1.0f / 2048.0f;  // (pi/1024) / (2*pi)
  float r0 = p * (float)(j + 0) * inv;
  float r1 = p * (float)(j + 1) * inv;
  float r2 = p * (float)(j + 2) * inv;
  float r3 = p * (float)(j + 3) * inv;
  float s1 = __builtin_amdgcn_sinf(r0 - floorf(r0));
  float c0 = __builtin_amdgcn_cosf(r1 - floorf(r1));
  float s3 = __builtin_amdgcn_sinf(r2 - floorf(r2));
  float c2 = __builtin_amdgcn_cosf(r3 - floorf(r3));
  ushort4 o;
  o.x = f2bf(c0 * xv.y);
  o.y = f2bf(s1 * xv.x);
  o.z = f2bf(c2 * xv.w);
  o.w = f2bf(s3 * xv.z);
  *(ushort4*)(out + base + j) = o;
  if (out2) *(ushort4*)(out2 + base + j) = o;
  if (raw) {
    ushort4 rw; rw.x = f2bf(xv.x); rw.y = f2bf(xv.y); rw.z = f2bf(xv.z); rw.w = f2bf(xv.w);
    *(ushort4*)(raw + base + j) = rw;
  }
}

// ---------------- split (4096,3072) projection into per-head Q,K,V^T ----------------
__global__ __launch_bounds__(256) void split_qkv_kernel(const u16* __restrict__ P,
                                                        u16* __restrict__ Qb,
                                                        u16* __restrict__ Kb,
                                                        u16* __restrict__ Vtb) {
  long e = ((long)blockIdx.x * 256 + threadIdx.x) * 8;
  int m = (int)(e / 3072);
  int n = (int)(e % 3072);
  int t = m >> 2, b = m & 3;
  int sec = n >> 10, nn = n & 1023;
  int h = nn >> 6, d = nn & 63;
  long bh = b * 16 + h;
  u16x8 v = *(const u16x8*)(P + e);
  if (sec == 0) {
    *(u16x8*)(Qb + (bh << 16) + ((long)t << 6) + d) = v;
  } else if (sec == 1) {
    *(u16x8*)(Kb + (bh << 16) + ((long)t << 6) + d) = v;
  } else {
    u16* dst = Vtb + (bh << 16) + ((long)d << 10) + t;
#pragma unroll
    for (int q = 0; q < 8; q++) dst[(long)q << 10] = v[q];
  }
}

// ---------------- flash attention: staged K/V, swapped QK^T, exp2 + defer-max ------
// Q (pre-scaled by 0.125*log2e), K: [bh][t][64]; Vt: [bh][64][1024]; AO: (t,b,e).
// Swapped S^T = mfma(K,Q): lane owns q-row (lane&15); row-reduce = 2 shfl stages.
__global__ __launch_bounds__(256) void fattn_kernel(const u16* __restrict__ Q,
                                                    const u16* __restrict__ K,
                                                    const u16* __restrict__ Vt,
                                                    u16* __restrict__ AO,
                                                    float2* __restrict__ Ml) {
  __shared__ u16 lK[2][4096];
  __shared__ u16 lV[2][4096];
  __shared__ u16 lP[4][1024];
  const int tid = threadIdx.x, lane = tid & 63, wid = tid >> 6;
  const int nb = gridDim.x * gridDim.y;
  const int orig = blockIdx.y * gridDim.x + blockIdx.x;
  const int swz = (orig & 7) * (nb >> 3) + (orig >> 3);
  const int qt = swz & 15;
  const int bh = swz >> 4;
  const int b = bh >> 4, h = bh & 15;
  const u16* Qp = Q + ((long)bh << 16);
  const u16* Kp = K + ((long)bh << 16);
  const u16* Vp = Vt + ((long)bh << 16);
  const int q0 = qt << 6;
  const int cr = lane >> 4;

  short8 af0, af1;  // Q fragment (B-operand): row = lane&15 = q-row within wave block
  {
    const u16* qs = Qp + (long)(q0 + wid * 16 + (lane & 15)) * 64 + cr * 8;
    af0 = *(const short8*)qs;
    af1 = *(const short8*)(qs + 32);
  }

  float m = -1e30f, l = 0.f;  // per-lane scalar: softmax state of q = lane&15
  f32x4 acco[4] = {};

  auto stage = [&](int bufi, int kv) {
    int s0 = kv << 6;
#pragma unroll
    for (int it = 0; it < 2; it++) {
      int c = it * 256 + tid;
      int row = c >> 3, ch = c & 7;
      int sch = (ch ^ (row & 7)) * 8;  // pre-swizzled source, linear LDS dst
      GLOAD16(Kp + (long)(s0 + row) * 64 + sch, &lK[bufi][c * 8]);
      GLOAD16(Vp + (long)row * 1024 + s0 + sch, &lV[bufi][c * 8]);
    }
  };

  stage(0, 0);
  __syncthreads();
  int buf = 0;
  for (int kv = 0; kv < 16; kv++) {
    if (kv < 15) stage(buf ^ 1, kv + 1);
    // S^T tile: accs[j][r] = S[q=lane&15][kv = j*16 + cr*4 + r]
    f32x4 accs[4];
    __builtin_amdgcn_s_setprio(1);
#pragma unroll
    for (int j = 0; j < 4; j++) {
      int sr = j * 16 + (lane & 15);
      const short8 kf0 = *(const short8*)&lK[buf][sr * 64 + ((cr ^ (sr & 7)) * 8)];
      const short8 kf1 = *(const short8*)&lK[buf][sr * 64 + (((4 + cr) ^ (sr & 7)) * 8)];
      f32x4 zz = {};
      zz = __builtin_amdgcn_mfma_f32_16x16x32_bf16(kf0, af0, zz, 0, 0, 0);
      accs[j] = __builtin_amdgcn_mfma_f32_16x16x32_bf16(kf1, af1, zz, 0, 0, 0);
    }
    __builtin_amdgcn_s_setprio(0);
    // row max: 15 local fmax + 2 shfl stages (partners lane^16, lane^32)
    float tm = fmaxf(fmaxf(fmaxf(accs[0][0], accs[0][1]), fmaxf(accs[0][2], accs[0][3])),
                     fmaxf(fmaxf(accs[1][0], accs[1][1]), fmaxf(accs[1][2], accs[1][3])));
    float tm2 = fmaxf(fmaxf(fmaxf(accs[2][0], accs[2][1]), fmaxf(accs[2][2], accs[2][3])),
                      fmaxf(fmaxf(accs[3][0], accs[3][1]), fmaxf(accs[3][2], accs[3][3])));
    tm = fmaxf(tm, tm2);
    tm = fmaxf(tm, __shfl_xor(tm, 16));
    tm = fmaxf(tm, __shfl_xor(tm, 32));
    // defer-max: rescale only when max grew by > 8 (P bounded by 2^8)
    if (!__all(tm - m <= 8.0f)) {
      float mn = fmaxf(m, tm);
      float f = __builtin_amdgcn_exp2f(m - mn);
      m = mn; l *= f;
      // acco rows are q = cr*4+r -> fetch that q's factor (lane q holds it)
#pragma unroll
      for (int r = 0; r < 4; r++) {
        float fr = __shfl(f, cr * 4 + r);
        acco[0][r] *= fr; acco[1][r] *= fr; acco[2][r] *= fr; acco[3][r] *= fr;
      }
    }
    float rs = 0.f;
#pragma unroll
    for (int j = 0; j < 4; j++)
#pragma unroll
      for (int r = 0; r < 4; r++) {
        float p = __builtin_amdgcn_exp2f(accs[j][r] - m);
        accs[j][r] = p;
        rs += p;
      }
    rs += __shfl_xor(rs, 16);
    rs += __shfl_xor(rs, 32);
    l += rs;
    // P -> wave-private swizzled LDS: lane writes row q=lane&15, kv=j*16+cr*4+{0..3}
    {
      u16* pw = lP[wid];
      int q = lane & 15;
      int rowoff = q * 64;
      int qs7 = q & 7;
#pragma unroll
      for (int j = 0; j < 4; j++) {
        uint2 pk;
        asm("v_cvt_pk_bf16_f32 %0, %1, %2"
            : "=v"(pk.x) : "v"(accs[j][0]), "v"(accs[j][1]));
        asm("v_cvt_pk_bf16_f32 %0, %1, %2"
            : "=v"(pk.y) : "v"(accs[j][2]), "v"(accs[j][3]));
        int chunk = 2 * j + (cr >> 1);
        int idx = rowoff + ((chunk ^ qs7) * 8) + 4 * (cr & 1);
        *(uint2*)(pw + idx) = pk;
      }
    }
    // PV accumulate (compiler inserts the lgkmcnt wait for the LDS dep)
    {
      int ql = lane & 15;
      const u16* pr = &lP[wid][ql * 64];
      short8 pa0 = *(const short8*)&pr[(cr ^ (ql & 7)) * 8];
      short8 pa1 = *(const short8*)&pr[((4 + cr) ^ (ql & 7)) * 8];
      __builtin_amdgcn_s_setprio(1);
#pragma unroll
      for (int j = 0; j < 4; j++) {
        int dr = j * 16 + (lane & 15);
        const short8 vf0 = *(const short8*)&lV[buf][dr * 64 + ((cr ^ (dr & 7)) * 8)];
        const short8 vf1 = *(const short8*)&lV[buf][dr * 64 + (((4 + cr) ^ (dr & 7)) * 8)];
        acco[j] = __builtin_amdgcn_mfma_f32_16x16x32_bf16(pa0, vf0, acco[j], 0, 0, 0);
        acco[j] = __builtin_amdgcn_mfma_f32_16x16x32_bf16(pa1, vf1, acco[j], 0, 0, 0);
      }
      __builtin_amdgcn_s_setprio(0);
    }
    __syncthreads();
    buf ^= 1;
  }
  float invl = 1.0f / l;
  float ilr[4];
#pragma unroll
  for (int r = 0; r < 4; r++) ilr[r] = __shfl(invl, cr * 4 + r);
#pragma unroll
  for (int j = 0; j < 4; j++)
#pragma unroll
    for (int r = 0; r < 4; r++) {
      int t = q0 + wid * 16 + cr * 4 + r;
      int e = (b << 10) + (h << 6) + j * 16 + (lane & 15);
      AO[(long)t * 4096 + e] = f2bf(acco[j][r] * ilr[r]);
    }
  if (Ml && lane < 16) {
    int t = q0 + wid * 16 + lane;
    Ml[((long)bh << 10) + t] = make_float2(m, invl);
  }
}

// ---------------- ws recompute: ws[b][l][s] = 1/16 sum_h exp2(S'-m)*invl ----------
// Staged K (double-buffered across heads); deterministic tile ownership.
__global__ __launch_bounds__(256) void wsrec_kernel(const u16* __restrict__ Q,
                                                    const u16* __restrict__ K,
                                                    const float2* __restrict__ Ml,
                                                    float* __restrict__ ws) {
  __shared__ u16 lK[2][4096];
  const int tid = threadIdx.x, lane = tid & 63, wid = tid >> 6;
  const int nb = gridDim.x * gridDim.y;  // 256
  const int orig = blockIdx.y * gridDim.x + blockIdx.x;
  const int swz = (orig & 7) * (nb >> 3) + (orig >> 3);
  const int st = swz & 15, lt = swz >> 4;
  const int b = blockIdx.z;
  const int s0 = st << 6, l0 = lt << 6;
  const int cr = lane >> 4;

  auto stage = [&](int bufi, int h) {
    const u16* Kp = K + (((long)(b * 16 + h)) << 16);
#pragma unroll
    for (int it = 0; it < 2; it++) {
      int c = it * 256 + tid;
      int row = c >> 3, ch = c & 7;
      GLOAD16(Kp + (long)(s0 + row) * 64 + ((ch ^ (row & 7)) * 8), &lK[bufi][c * 8]);
    }
  };

  f32x4 wacc[4] = {};
  stage(0, 0);
  __syncthreads();
  int buf = 0;
  for (int h = 0; h < 16; h++) {
    if (h < 15) stage(buf ^ 1, h + 1);
    const int bh = b * 16 + h;
    short8 af0, af1;
    {
      const u16* qs = Q + ((long)bh << 16) + (long)(l0 + wid * 16 + (lane & 15)) * 64 + cr * 8;
      af0 = *(const short8*)qs;
      af1 = *(const short8*)(qs + 32);
    }
    f32x4 accs[4];
    __builtin_amdgcn_s_setprio(1);
#pragma unroll
    for (int j = 0; j < 4; j++) {
      int sr = j * 16 + (lane & 15);
      const short8 kf0 = *(const short8*)&lK[buf][sr * 64 + ((cr ^ (sr & 7)) * 8)];
      const short8 kf1 = *(const short8*)&lK[buf][sr * 64 + (((4 + cr) ^ (sr & 7)) * 8)];
      f32x4 zz = {};
      zz = __builtin_amdgcn_mfma_f32_16x16x32_bf16(af0, kf0, zz, 0, 0, 0);
      accs[j] = __builtin_amdgcn_mfma_f32_16x16x32_bf16(af1, kf1, zz, 0, 0, 0);
    }
    __builtin_amdgcn_s_setprio(0);
    float mm[4], il[4];
#pragma unroll
    for (int r = 0; r < 4; r++) {
      float2 v = Ml[((long)bh << 10) + l0 + wid * 16 + (lane >> 4) * 4 + r];
      mm[r] = v.x; il[r] = v.y * 0.0625f;
    }
#pragma unroll
    for (int j = 0; j < 4; j++)
#pragma unroll
      for (int r = 0; r < 4; r++)
        wacc[j][r] += __builtin_amdgcn_exp2f(accs[j][r] - mm[r]) * il[r];
    __syncthreads();
    buf ^= 1;
  }
#pragma unroll
  for (int j = 0; j < 4; j++)
#pragma unroll
    for (int r = 0; r < 4; r++) {
      int li = l0 + wid * 16 + (lane >> 4) * 4 + r;
      int si = s0 + j * 16 + (lane & 15);
      ws[((long)b << 20) + (long)li * 1024 + si] = wacc[j][r];
    }
}

// ---------------- layernorm (ddof=1): x = X + D1 [+ D2] [+ bo]; LN(x) ----------------
__global__ __launch_bounds__(256) void ln_kernel(const float* __restrict__ X,
                                                 const float* __restrict__ D1,
                                                 const float* __restrict__ D2,
                                                 const float* __restrict__ bo,
                                                 const float* __restrict__ g,
                                                 const float* __restrict__ be,
                                                 float* __restrict__ out,
                                                 u16* __restrict__ bfout) {
  int mrow = blockIdx.x;
  int tid = threadIdx.x, lane = tid & 63, wid = tid >> 6;
  long base = ((long)mrow << 10);
  float4 a = *(const float4*)(X + base + tid * 4);
  float4 b = *(const float4*)(D1 + base + tid * 4);
  float x0 = a.x + b.x, x1 = a.y + b.y, x2 = a.z + b.z, x3 = a.w + b.w;
  if (D2) {
    float4 c = *(const float4*)(D2 + base + tid * 4);
    x0 += c.x; x1 += c.y; x2 += c.z; x3 += c.w;
  }
  if (bo) {
    float4 c = *(const float4*)(bo + tid * 4);
    x0 += c.x; x1 += c.y; x2 += c.z; x3 += c.w;
  }
  float s = x0 + x1 + x2 + x3;
#pragma unroll
  for (int o = 32; o; o >>= 1) s += __shfl_xor(s, o);
  __shared__ float red[4];
  if (lane == 0) red[wid] = s;
  __syncthreads();
  float mean = (red[0] + red[1] + red[2] + red[3]) * (1.0f / 1024.0f);
  float d0 = x0 - mean, d1 = x1 - mean, d2 = x2 - mean, d3 = x3 - mean;
  float ss = d0 * d0 + d1 * d1 + d2 * d2 + d3 * d3;
#pragma unroll
  for (int o = 32; o; o >>= 1) ss += __shfl_xor(ss, o);
  __syncthreads();
  if (lane == 0) red[wid] = ss;
  __syncthreads();
  float var = (red[0] + red[1] + red[2] + red[3]) * (1.0f / 1023.0f);
  float sc = 1.0f / sqrtf(var + 1e-5f);
  float4 gv = *(const float4*)(g + tid * 4);
  float4 bv = *(const float4*)(be + tid * 4);
  float y0 = gv.x * d0 * sc + bv.x;
  float y1 = gv.y * d1 * sc + bv.y;
  float y2 = gv.z * d2 * sc + bv.z;
  float y3 = gv.w * d3 * sc + bv.w;
  float4 o4; o4.x = y0; o4.y = y1; o4.z = y2; o4.w = y3;
  *(float4*)(out + base + tid * 4) = o4;
  if (bfout) {
    ushort4 hh; hh.x = f2bf(y0); hh.y = f2bf(y1); hh.z = f2bf(y2); hh.w = f2bf(y3);
    *(ushort4*)(bfout + base + tid * 4) = hh;
  }
}

// ---------------- out = X + P0 + P1 + b[col] ----------------
__global__ __launch_bounds__(256) void add3_kernel(const float* __restrict__ X,
                                                   const float* __restrict__ P0,
                                                   const float* __restrict__ P1,
                                                   const float* __restrict__ b,
                                                   float* __restrict__ out) {
  long i = ((long)blockIdx.x * 256 + threadIdx.x) * 4;
  int col = (int)(i & 1023);
  float4 x = *(const float4*)(X + i);
  float4 p = *(const float4*)(P0 + i);
  float4 q = *(const float4*)(P1 + i);
  float4 bb = *(const float4*)(b + col);
  float4 o;
  o.x = x.x + p.x + q.x + bb.x;
  o.y = x.y + p.y + q.y + bb.y;
  o.z = x.z + p.z + q.z + bb.z;
  o.w = x.w + p.w + q.w + bb.w;
  *(float4*)(out + i) = o;
}

// ---------------- BT GEMM: C(MxN) = alpha * A(MxK) * B(NxK)^T
// flags: 1=bias per col (bias + z*sbz), 2=relu, 4=f32 output (else bf16),
//        8 = alpha applied only to z==0 AFTER bias (for Q log2-domain pre-scale)
template <int BM, int BN, int BK, int WR, int WC, int NT, int DB>
__global__ __launch_bounds__(NT)
void gemm_bt_kernel(const u16* __restrict__ A, const u16* __restrict__ B,
                    void* __restrict__ C, const float* __restrict__ bias,
                    int lda, int ldb, int ldc, int K,
                    long sAz, long sBz, long sCz, long sbz,
                    float alpha, int flags) {
  constexpr int WTM = BM / WR, WTN = BN / WC;
  constexpr int FM = WTM / 16, FN = WTN / 16;
  constexpr int NC = BK / 8;
  __shared__ u16 lA[DB][BM * BK];
  __shared__ u16 lB[DB][BN * BK];
  const int tid = threadIdx.x, lane = tid & 63, wid = tid >> 6;
  const int wr = wid / WC, wc = wid % WC;
  const int z = blockIdx.z;

  const int nwg = gridDim.x * gridDim.y;
  const int orig = blockIdx.y * gridDim.x + blockIdx.x;
  const int qq = nwg >> 3, rr = nwg & 7;
  const int xcd = orig & 7, idx = orig >> 3;
  const int swz = (xcd < rr ? xcd * (qq + 1) : rr * (qq + 1) + (xcd - rr) * qq) + idx;
  const int bxs = swz % gridDim.x;
  const int bys = swz / gridDim.x;

  const u16* Ab = A + z * sAz + (long)bys * BM * lda;
  const u16* Bb = B + z * sBz + (long)bxs * BN * ldb;

  f32x4 acc[FM][FN] = {};

  auto stage = [&](int bufi, int k0) {
#pragma unroll
    for (int c0 = 0; c0 < BM * NC; c0 += NT) {
      int c = c0 + tid;
      if ((BM * NC) % NT == 0 || c < BM * NC) {
        int row = c / NC, ch = c % NC;
        int sch = ch ^ SWZ(BK, row);
        GLOAD16(Ab + (long)row * lda + k0 + sch * 8, &lA[bufi][c * 8]);
      }
    }
#pragma unroll
    for (int c0 = 0; c0 < BN * NC; c0 += NT) {
      int c = c0 + tid;
      if ((BN * NC) % NT == 0 || c < BN * NC) {
        int row = c / NC, ch = c % NC;
        int sch = ch ^ SWZ(BK, row);
        GLOAD16(Bb + (long)row * ldb + k0 + sch * 8, &lB[bufi][c * 8]);
      }
    }
  };

  auto compute = [&](int bufi) {
#pragma unroll
    for (int kk = 0; kk < BK / 32; kk++) {
      short8 afv[FM], bfv[FN];
#pragma unroll
      for (int i = 0; i < FM; i++) {
        int row = wr * WTM + i * 16 + (lane & 15);
        int ch = kk * 4 + (lane >> 4);
        afv[i] = *(const short8*)&lA[bufi][row * BK + ((ch ^ SWZ(BK, row)) * 8)];
      }
#pragma unroll
      for (int j = 0; j < FN; j++) {
        int row = wc * WTN + j * 16 + (lane & 15);
        int ch = kk * 4 + (lane >> 4);
        bfv[j] = *(const short8*)&lB[bufi][row * BK + ((ch ^ SWZ(BK, row)) * 8)];
      }
#pragma unroll
      for (int i = 0; i < FM; i++)
#pragma unroll
        for (int j = 0; j < FN; j++)
          acc[i][j] = __builtin_amdgcn_mfma_f32_16x16x32_bf16(afv[i], bfv[j], acc[i][j], 0, 0, 0);
    }
  };

  const int nk = K / BK;
  if (DB == 2) {
    stage(0, 0);
    __syncthreads();
    int cur = 0;
    for (int t = 0; t < nk; t++) {
      if (t + 1 < nk) stage(cur ^ 1, (t + 1) * BK);
      compute(cur);
      __syncthreads();
      cur ^= 1;
    }
  } else {
    for (int t = 0; t < nk; t++) {
      stage(0, t * BK);
      __syncthreads();
      compute(0);
      __syncthreads();
    }
  }

  const long rbase = (long)bys * BM + wr * WTM;
  const int cbase = bxs * BN + wc * WTN;
  const float* bz = bias ? (bias + z * sbz) : nullptr;
#pragma unroll
  for (int i = 0; i < FM; i++)
#pragma unroll
    for (int j = 0; j < FN; j++)
#pragma unroll
      for (int r = 0; r < 4; r++) {
        long row = rbase + i * 16 + ((lane >> 4) * 4 + r);
        int col = cbase + j * 16 + (lane & 15);
        float v = acc[i][j][r];
        if (!(flags & 8)) v *= alpha;
        if (flags & 1) v += bz[col];
        if ((flags & 8) && z == 0) v *= alpha;
        if (flags & 2) v = fmaxf(v, 0.0f);
        long off = (long)z * sCz + row * (long)ldc + col;
        if (flags & 4) ((float*)C)[off] = v;
        else ((u16*)C)[off] = f2bf(v);
      }
}

extern "C" void kernel_launch(void* const* d_in, const int* in_sizes, int n_in,
                              void* d_out, int out_size, void* d_ws, size_t ws_size,
                              hipStream_t stream) {
  const float* tgt  = (const float*)d_in[0];
  const float* mem  = (const float*)d_in[1];
  const float* pos  = (const float*)d_in[2];
  const float* qpos = (const float*)d_in[3];
  const float* wqkvS = (const float*)d_in[4];
  const float* bqkvS = (const float*)d_in[5];
  const float* woS   = (const float*)d_in[6];
  const float* boS   = (const float*)d_in[7];
  const float* wqkvC = (const float*)d_in[8];
  const float* bqkvC = (const float*)d_in[9];
  const float* woC   = (const float*)d_in[10];
  const float* boC   = (const float*)d_in[11];
  const float* w1  = (const float*)d_in[12];
  const float* b1  = (const float*)d_in[13];
  const float* w2  = (const float*)d_in[14];
  const float* b2  = (const float*)d_in[15];
  const float* g1  = (const float*)d_in[16];
  const float* be1 = (const float*)d_in[17];
  const float* g2  = (const float*)d_in[18];
  const float* be2 = (const float*)d_in[19];

  const size_t MB = 1024ull * 1024ull;
  float* out0 = (float*)d_out;
  float* wsout = out0 + 4194304;

  // ---- workspace schedule (time-shared, non-overlapping; 136MB total) ----
  char* W = (char*)d_ws;
  u16* wb = (u16*)W;
  u16* wqkvS_b = wb;
  u16* woS_b   = wb + 3145728;
  u16* wqkvC_b = wb + 4194304;
  u16* woC_b   = wb + 7340032;
  u16* w1_b    = wb + 8388608;
  u16* w2_b    = wb + 12582912;
  float* Xf   = (float*)(W + 32 * MB);
  float* OPar = (float*)(W + 48 * MB);
  u16* Pq  = (u16*)(W + 48 * MB);
  u16* bf1 = (u16*)(W + 80 * MB);
  u16* bf2 = (u16*)(W + 88 * MB);
  u16* bf3 = (u16*)(W + 96 * MB);
  float2* Ml = (float2*)(W + 96 * MB);  // 512KB; lives after QKV proj consumed bf3
  u16* Qb  = (u16*)(W + 104 * MB);
  u16* Kb  = (u16*)(W + 112 * MB);
  u16* Vtb = (u16*)(W + 120 * MB);
  u16* AOb = (u16*)(W + 128 * MB);
  u16* F1  = (u16*)(W + 104 * MB);

  // all weights -> bf16, one launch
  wcvt_kernel<<<16384, 256, 0, stream>>>(wqkvS, woS, wqkvC, woC, w1, w2, wb);

  // ================= self attention =================
  pos_embed_kernel<<<4096, 256, 0, stream>>>(tgt, qpos, bf1, bf2, bf3);
  gemm_bt_kernel<256, 128, 32, 2, 4, 512, 2><<<dim3(8, 16, 3), 512, 0, stream>>>(
      bf1, wqkvS_b, Pq, bqkvS, 1024, 1024, 3072, 1024,
      4194304, 1048576, 1024, 1024, QSCALE, 1 | 8);
  split_qkv_kernel<<<6144, 256, 0, stream>>>(Pq, Qb, Kb, Vtb);
  fattn_kernel<<<dim3(16, 64), 256, 0, stream>>>(Qb, Kb, Vtb, AOb, nullptr);
  gemm_bt_kernel<256, 128, 32, 2, 4, 512, 2><<<dim3(8, 16, 2), 512, 0, stream>>>(
      AOb, woS_b, OPar, nullptr, 1024, 1024, 1024, 512,
      512, 512, 4194304, 0, 1.0f, 4);
  ln_kernel<<<4096, 256, 0, stream>>>(tgt, OPar, OPar + 4194304, boS, g1, be1, Xf, nullptr);

  // ================= cross attention =================
  pos_embed_kernel<<<4096, 256, 0, stream>>>(Xf, qpos, bf1, nullptr, nullptr);
  pos_embed_kernel<<<4096, 256, 0, stream>>>(mem, pos, bf2, nullptr, bf3);
  gemm_bt_kernel<256, 128, 32, 2, 4, 512, 2><<<dim3(8, 16, 3), 512, 0, stream>>>(
      bf1, wqkvC_b, Pq, bqkvC, 1024, 1024, 3072, 1024,
      4194304, 1048576, 1024, 1024, QSCALE, 1 | 8);
  split_qkv_kernel<<<6144, 256, 0, stream>>>(Pq, Qb, Kb, Vtb);
  fattn_kernel<<<dim3(16, 64), 256, 0, stream>>>(Qb, Kb, Vtb, AOb, Ml);
  wsrec_kernel<<<dim3(16, 16, 4), 256, 0, stream>>>(Qb, Kb, Ml, wsout);
  gemm_bt_kernel<256, 128, 32, 2, 4, 512, 2><<<dim3(8, 16, 2), 512, 0, stream>>>(
      AOb, woC_b, OPar, nullptr, 1024, 1024, 1024, 512,
      512, 512, 4194304, 0, 1.0f, 4);
  ln_kernel<<<4096, 256, 0, stream>>>(Xf, OPar, OPar + 4194304, boC, g2, be2, Xf, bf1);

  // ================= FFN =================
  gemm_bt_kernel<256, 128, 32, 2, 4, 512, 2><<<dim3(32, 16, 1), 512, 0, stream>>>(
      bf1, w1_b, F1, b1, 1024, 1024, 4096, 1024, 0, 0, 0, 0, 1.0f, 1 | 2);
  gemm_bt_kernel<256, 128, 32, 2, 4, 512, 2><<<dim3(8, 16, 2), 512, 0, stream>>>(
      F1, w2_b, OPar, nullptr, 4096, 4096, 1024, 2048,
      2048, 2048, 4194304, 0, 1.0f, 4);
  add3_kernel<<<4096, 256, 0, stream>>>(Xf, OPar, OPar + 4194304, b2, out0);
}

// Round 10
// 447.347 us; speedup vs baseline: 1.0458x; 1.0458x over previous
//
#include <hip/hip_runtime.h>

typedef unsigned short u16;
typedef __attribute__((ext_vector_type(8))) short short8;
typedef __attribute__((ext_vector_type(8))) unsigned short u16x8;
typedef __attribute__((ext_vector_type(4))) float f32x4;

#define GLOAD16(SRC, DST) __builtin_amdgcn_global_load_lds( \
    (const __attribute__((address_space(1))) void*)(SRC),   \
    (__attribute__((address_space(3))) void*)(DST), 16, 0, 0)

// LDS chunk swizzle: spreads a column of 16B chunks across bank-groups.
#define SWZ(BKv, r) ((BKv) == 32 ? (((r) >> 1) & 3) : ((r) & 7))

// 0.125 * log2(e): folds softmax scale + exp->exp2 conversion into Q projection
#define QSCALE 0.18033688011112042f

__device__ __forceinline__ u16 f2bf(float f) {
  union { float f; unsigned u; } v; v.f = f;
  unsigned r = v.u + 0x7fffu + ((v.u >> 16) & 1u);
  return (u16)(r >> 16);
}
__device__ __forceinline__ float bf2f(u16 h) {
  union { unsigned u; float f; } v; v.u = ((unsigned)h) << 16;
  return v.f;
}

// ---------------- fused weights f32 -> bf16 convert (6 segments, contiguous dst) ----
__global__ __launch_bounds__(256) void wcvt_kernel(const float* __restrict__ s0,
                                                   const float* __restrict__ s1,
                                                   const float* __restrict__ s2,
                                                   const float* __restrict__ s3,
                                                   const float* __restrict__ s4,
                                                   const float* __restrict__ s5,
                                                   u16* __restrict__ dst) {
  long i = ((long)blockIdx.x * 256 + threadIdx.x) * 4;
  const float* src; long off;
  if (i < 3145728)        { src = s0; off = 0; }
  else if (i < 4194304)   { src = s1; off = 3145728; }
  else if (i < 7340032)   { src = s2; off = 4194304; }
  else if (i < 8388608)   { src = s3; off = 7340032; }
  else if (i < 12582912)  { src = s4; off = 8388608; }
  else                    { src = s5; off = 12582912; }
  float4 v = *(const float4*)(src + (i - off));
  ushort4 o; o.x = f2bf(v.x); o.y = f2bf(v.y); o.z = f2bf(v.z); o.w = f2bf(v.w);
  *(ushort4*)(dst + i) = o;
}

// ---------------- pos embed (revolution-domain v_sin/v_cos) + optional raw cast ----
__global__ __launch_bounds__(256) void pos_embed_kernel(const float* __restrict__ x,
                                                        const float* __restrict__ pos,
                                                        u16* __restrict__ out,
                                                        u16* __restrict__ out2,
                                                        u16* __restrict__ raw) {
  int m = blockIdx.x;
  int tid = threadIdx.x;
  float p = pos[m];
  long base = ((long)m << 10);
  int j = tid * 4;
  float4 xv = *(const float4*)(x + base + j);
  const float inv = 1.0f / 2048.0f;  // (pi/1024) / (2*pi)
  float r0 = p * (float)(j + 0) * inv;
  float r1 = p * (float)(j + 1) * inv;
  float r2 = p * (float)(j + 2) * inv;
  float r3 = p * (float)(j + 3) * inv;
  float s1 = __builtin_amdgcn_sinf(r0 - floorf(r0));
  float c0 = __builtin_amdgcn_cosf(r1 - floorf(r1));
  float s3 = __builtin_amdgcn_sinf(r2 - floorf(r2));
  float c2 = __builtin_amdgcn_cosf(r3 - floorf(r3));
  ushort4 o;
  o.x = f2bf(c0 * xv.y);
  o.y = f2bf(s1 * xv.x);
  o.z = f2bf(c2 * xv.w);
  o.w = f2bf(s3 * xv.z);
  *(ushort4*)(out + base + j) = o;
  if (out2) *(ushort4*)(out2 + base + j) = o;
  if (raw) {
    ushort4 rw; rw.x = f2bf(xv.x); rw.y = f2bf(xv.y); rw.z = f2bf(xv.z); rw.w = f2bf(xv.w);
    *(ushort4*)(raw + base + j) = rw;
  }
}

// ---------------- split (4096,3072) projection into per-head Q,K,V^T ----------------
__global__ __launch_bounds__(256) void split_qkv_kernel(const u16* __restrict__ P,
                                                        u16* __restrict__ Qb,
                                                        u16* __restrict__ Kb,
                                                        u16* __restrict__ Vtb) {
  long e = ((long)blockIdx.x * 256 + threadIdx.x) * 8;
  int m = (int)(e / 3072);
  int n = (int)(e % 3072);
  int t = m >> 2, b = m & 3;
  int sec = n >> 10, nn = n & 1023;
  int h = nn >> 6, d = nn & 63;
  long bh = b * 16 + h;
  u16x8 v = *(const u16x8*)(P + e);
  if (sec == 0) {
    *(u16x8*)(Qb + (bh << 16) + ((long)t << 6) + d) = v;
  } else if (sec == 1) {
    *(u16x8*)(Kb + (bh << 16) + ((long)t << 6) + d) = v;
  } else {
    u16* dst = Vtb + (bh << 16) + ((long)d << 10) + t;
#pragma unroll
    for (int q = 0; q < 8; q++) dst[(long)q << 10] = v[q];
  }
}

// ---------------- flash attention: staged K/V, swapped QK^T, exp2 + defer-max ------
__global__ __launch_bounds__(256) void fattn_kernel(const u16* __restrict__ Q,
                                                    const u16* __restrict__ K,
                                                    const u16* __restrict__ Vt,
                                                    u16* __restrict__ AO,
                                                    float2* __restrict__ Ml) {
  __shared__ u16 lK[2][4096];
  __shared__ u16 lV[2][4096];
  __shared__ u16 lP[4][1024];
  const int tid = threadIdx.x, lane = tid & 63, wid = tid >> 6;
  const int nb = gridDim.x * gridDim.y;
  const int orig = blockIdx.y * gridDim.x + blockIdx.x;
  const int swz = (orig & 7) * (nb >> 3) + (orig >> 3);
  const int qt = swz & 15;
  const int bh = swz >> 4;
  const int b = bh >> 4, h = bh & 15;
  const u16* Qp = Q + ((long)bh << 16);
  const u16* Kp = K + ((long)bh << 16);
  const u16* Vp = Vt + ((long)bh << 16);
  const int q0 = qt << 6;
  const int cr = lane >> 4;

  short8 af0, af1;  // Q fragment (B-operand): row = lane&15 = q-row within wave block
  {
    const u16* qs = Qp + (long)(q0 + wid * 16 + (lane & 15)) * 64 + cr * 8;
    af0 = *(const short8*)qs;
    af1 = *(const short8*)(qs + 32);
  }

  float m = -1e30f, l = 0.f;  // per-lane scalar: softmax state of q = lane&15
  f32x4 acco[4] = {};

  auto stage = [&](int bufi, int kv) {
    int s0 = kv << 6;
#pragma unroll
    for (int it = 0; it < 2; it++) {
      int c = it * 256 + tid;
      int row = c >> 3, ch = c & 7;
      int sch = (ch ^ (row & 7)) * 8;  // pre-swizzled source, linear LDS dst
      GLOAD16(Kp + (long)(s0 + row) * 64 + sch, &lK[bufi][c * 8]);
      GLOAD16(Vp + (long)row * 1024 + s0 + sch, &lV[bufi][c * 8]);
    }
  };

  stage(0, 0);
  __syncthreads();
  int buf = 0;
  for (int kv = 0; kv < 16; kv++) {
    if (kv < 15) stage(buf ^ 1, kv + 1);
    // S^T tile: accs[j][r] = S[q=lane&15][kv = j*16 + cr*4 + r]
    f32x4 accs[4];
    __builtin_amdgcn_s_setprio(1);
#pragma unroll
    for (int j = 0; j < 4; j++) {
      int sr = j * 16 + (lane & 15);
      const short8 kf0 = *(const short8*)&lK[buf][sr * 64 + ((cr ^ (sr & 7)) * 8)];
      const short8 kf1 = *(const short8*)&lK[buf][sr * 64 + (((4 + cr) ^ (sr & 7)) * 8)];
      f32x4 zz = {};
      zz = __builtin_amdgcn_mfma_f32_16x16x32_bf16(kf0, af0, zz, 0, 0, 0);
      accs[j] = __builtin_amdgcn_mfma_f32_16x16x32_bf16(kf1, af1, zz, 0, 0, 0);
    }
    __builtin_amdgcn_s_setprio(0);
    // row max: 15 local fmax + 2 shfl stages (partners lane^16, lane^32)
    float tm = fmaxf(fmaxf(fmaxf(accs[0][0], accs[0][1]), fmaxf(accs[0][2], accs[0][3])),
                     fmaxf(fmaxf(accs[1][0], accs[1][1]), fmaxf(accs[1][2], accs[1][3])));
    float tm2 = fmaxf(fmaxf(fmaxf(accs[2][0], accs[2][1]), fmaxf(accs[2][2], accs[2][3])),
                      fmaxf(fmaxf(accs[3][0], accs[3][1]), fmaxf(accs[3][2], accs[3][3])));
    tm = fmaxf(tm, tm2);
    tm = fmaxf(tm, __shfl_xor(tm, 16));
    tm = fmaxf(tm, __shfl_xor(tm, 32));
    // defer-max: rescale only when max grew by > 8 (P bounded by 2^8)
    if (!__all(tm - m <= 8.0f)) {
      float mn = fmaxf(m, tm);
      float f = __builtin_amdgcn_exp2f(m - mn);
      m = mn; l *= f;
#pragma unroll
      for (int r = 0; r < 4; r++) {
        float fr = __shfl(f, cr * 4 + r);
        acco[0][r] *= fr; acco[1][r] *= fr; acco[2][r] *= fr; acco[3][r] *= fr;
      }
    }
    float rs = 0.f;
#pragma unroll
    for (int j = 0; j < 4; j++)
#pragma unroll
      for (int r = 0; r < 4; r++) {
        float p = __builtin_amdgcn_exp2f(accs[j][r] - m);
        accs[j][r] = p;
        rs += p;
      }
    rs += __shfl_xor(rs, 16);
    rs += __shfl_xor(rs, 32);
    l += rs;
    // P -> wave-private swizzled LDS: lane writes row q=lane&15, kv=j*16+cr*4+{0..3}
    {
      u16* pw = lP[wid];
      int q = lane & 15;
      int rowoff = q * 64;
      int qs7 = q & 7;
#pragma unroll
      for (int j = 0; j < 4; j++) {
        uint2 pk;
        asm("v_cvt_pk_bf16_f32 %0, %1, %2"
            : "=v"(pk.x) : "v"(accs[j][0]), "v"(accs[j][1]));
        asm("v_cvt_pk_bf16_f32 %0, %1, %2"
            : "=v"(pk.y) : "v"(accs[j][2]), "v"(accs[j][3]));
        int chunk = 2 * j + (cr >> 1);
        int idx = rowoff + ((chunk ^ qs7) * 8) + 4 * (cr & 1);
        *(uint2*)(pw + idx) = pk;
      }
    }
    // PV accumulate (compiler inserts the lgkmcnt wait for the LDS dep)
    {
      int ql = lane & 15;
      const u16* pr = &lP[wid][ql * 64];
      short8 pa0 = *(const short8*)&pr[(cr ^ (ql & 7)) * 8];
      short8 pa1 = *(const short8*)&pr[((4 + cr) ^ (ql & 7)) * 8];
      __builtin_amdgcn_s_setprio(1);
#pragma unroll
      for (int j = 0; j < 4; j++) {
        int dr = j * 16 + (lane & 15);
        const short8 vf0 = *(const short8*)&lV[buf][dr * 64 + ((cr ^ (dr & 7)) * 8)];
        const short8 vf1 = *(const short8*)&lV[buf][dr * 64 + (((4 + cr) ^ (dr & 7)) * 8)];
        acco[j] = __builtin_amdgcn_mfma_f32_16x16x32_bf16(pa0, vf0, acco[j], 0, 0, 0);
        acco[j] = __builtin_amdgcn_mfma_f32_16x16x32_bf16(pa1, vf1, acco[j], 0, 0, 0);
      }
      __builtin_amdgcn_s_setprio(0);
    }
    __syncthreads();
    buf ^= 1;
  }
  float invl = 1.0f / l;
  float ilr[4];
#pragma unroll
  for (int r = 0; r < 4; r++) ilr[r] = __shfl(invl, cr * 4 + r);
#pragma unroll
  for (int j = 0; j < 4; j++)
#pragma unroll
    for (int r = 0; r < 4; r++) {
      int t = q0 + wid * 16 + cr * 4 + r;
      int e = (b << 10) + (h << 6) + j * 16 + (lane & 15);
      AO[(long)t * 4096 + e] = f2bf(acco[j][r] * ilr[r]);
    }
  if (Ml && lane < 16) {
    int t = q0 + wid * 16 + lane;
    Ml[((long)bh << 10) + t] = make_float2(m, invl);
  }
}

// ---------------- ws recompute: ws[b][l][s] = 1/16 sum_h exp2(S'-m)*invl ----------
__global__ __launch_bounds__(256) void wsrec_kernel(const u16* __restrict__ Q,
                                                    const u16* __restrict__ K,
                                                    const float2* __restrict__ Ml,
                                                    float* __restrict__ ws) {
  __shared__ u16 lK[2][4096];
  const int tid = threadIdx.x, lane = tid & 63, wid = tid >> 6;
  const int nb = gridDim.x * gridDim.y;  // 256
  const int orig = blockIdx.y * gridDim.x + blockIdx.x;
  const int swz = (orig & 7) * (nb >> 3) + (orig >> 3);
  const int st = swz & 15, lt = swz >> 4;
  const int b = blockIdx.z;
  const int s0 = st << 6, l0 = lt << 6;
  const int cr = lane >> 4;

  auto stage = [&](int bufi, int h) {
    const u16* Kp = K + (((long)(b * 16 + h)) << 16);
#pragma unroll
    for (int it = 0; it < 2; it++) {
      int c = it * 256 + tid;
      int row = c >> 3, ch = c & 7;
      GLOAD16(Kp + (long)(s0 + row) * 64 + ((ch ^ (row & 7)) * 8), &lK[bufi][c * 8]);
    }
  };

  f32x4 wacc[4] = {};
  stage(0, 0);
  __syncthreads();
  int buf = 0;
  for (int h = 0; h < 16; h++) {
    if (h < 15) stage(buf ^ 1, h + 1);
    const int bh = b * 16 + h;
    short8 af0, af1;
    {
      const u16* qs = Q + ((long)bh << 16) + (long)(l0 + wid * 16 + (lane & 15)) * 64 + cr * 8;
      af0 = *(const short8*)qs;
      af1 = *(const short8*)(qs + 32);
    }
    f32x4 accs[4];
    __builtin_amdgcn_s_setprio(1);
#pragma unroll
    for (int j = 0; j < 4; j++) {
      int sr = j * 16 + (lane & 15);
      const short8 kf0 = *(const short8*)&lK[buf][sr * 64 + ((cr ^ (sr & 7)) * 8)];
      const short8 kf1 = *(const short8*)&lK[buf][sr * 64 + (((4 + cr) ^ (sr & 7)) * 8)];
      f32x4 zz = {};
      zz = __builtin_amdgcn_mfma_f32_16x16x32_bf16(af0, kf0, zz, 0, 0, 0);
      accs[j] = __builtin_amdgcn_mfma_f32_16x16x32_bf16(af1, kf1, zz, 0, 0, 0);
    }
    __builtin_amdgcn_s_setprio(0);
    float mm[4], il[4];
#pragma unroll
    for (int r = 0; r < 4; r++) {
      float2 v = Ml[((long)bh << 10) + l0 + wid * 16 + (lane >> 4) * 4 + r];
      mm[r] = v.x; il[r] = v.y * 0.0625f;
    }
#pragma unroll
    for (int j = 0; j < 4; j++)
#pragma unroll
      for (int r = 0; r < 4; r++)
        wacc[j][r] += __builtin_amdgcn_exp2f(accs[j][r] - mm[r]) * il[r];
    __syncthreads();
    buf ^= 1;
  }
#pragma unroll
  for (int j = 0; j < 4; j++)
#pragma unroll
    for (int r = 0; r < 4; r++) {
      int li = l0 + wid * 16 + (lane >> 4) * 4 + r;
      int si = s0 + j * 16 + (lane & 15);
      ws[((long)b << 20) + (long)li * 1024 + si] = wacc[j][r];
    }
}

// ---------------- layernorm (ddof=1): x = X + D1 [+ D2] [+ bo]; LN(x) ----------------
__global__ __launch_bounds__(256) void ln_kernel(const float* __restrict__ X,
                                                 const float* __restrict__ D1,
                                                 const float* __restrict__ D2,
                                                 const float* __restrict__ bo,
                                                 const float* __restrict__ g,
                                                 const float* __restrict__ be,
                                                 float* __restrict__ out,
                                                 u16* __restrict__ bfout) {
  int mrow = blockIdx.x;
  int tid = threadIdx.x, lane = tid & 63, wid = tid >> 6;
  long base = ((long)mrow << 10);
  float4 a = *(const float4*)(X + base + tid * 4);
  float4 b = *(const float4*)(D1 + base + tid * 4);
  float x0 = a.x + b.x, x1 = a.y + b.y, x2 = a.z + b.z, x3 = a.w + b.w;
  if (D2) {
    float4 c = *(const float4*)(D2 + base + tid * 4);
    x0 += c.x; x1 += c.y; x2 += c.z; x3 += c.w;
  }
  if (bo) {
    float4 c = *(const float4*)(bo + tid * 4);
    x0 += c.x; x1 += c.y; x2 += c.z; x3 += c.w;
  }
  float s = x0 + x1 + x2 + x3;
#pragma unroll
  for (int o = 32; o; o >>= 1) s += __shfl_xor(s, o);
  __shared__ float red[4];
  if (lane == 0) red[wid] = s;
  __syncthreads();
  float mean = (red[0] + red[1] + red[2] + red[3]) * (1.0f / 1024.0f);
  float d0 = x0 - mean, d1 = x1 - mean, d2 = x2 - mean, d3 = x3 - mean;
  float ss = d0 * d0 + d1 * d1 + d2 * d2 + d3 * d3;
#pragma unroll
  for (int o = 32; o; o >>= 1) ss += __shfl_xor(ss, o);
  __syncthreads();
  if (lane == 0) red[wid] = ss;
  __syncthreads();
  float var = (red[0] + red[1] + red[2] + red[3]) * (1.0f / 1023.0f);
  float sc = 1.0f / sqrtf(var + 1e-5f);
  float4 gv = *(const float4*)(g + tid * 4);
  float4 bv = *(const float4*)(be + tid * 4);
  float y0 = gv.x * d0 * sc + bv.x;
  float y1 = gv.y * d1 * sc + bv.y;
  float y2 = gv.z * d2 * sc + bv.z;
  float y3 = gv.w * d3 * sc + bv.w;
  float4 o4; o4.x = y0; o4.y = y1; o4.z = y2; o4.w = y3;
  *(float4*)(out + base + tid * 4) = o4;
  if (bfout) {
    ushort4 hh; hh.x = f2bf(y0); hh.y = f2bf(y1); hh.z = f2bf(y2); hh.w = f2bf(y3);
    *(ushort4*)(bfout + base + tid * 4) = hh;
  }
}

// ---------------- out = X + P0 + P1 + b[col] ----------------
__global__ __launch_bounds__(256) void add3_kernel(const float* __restrict__ X,
                                                   const float* __restrict__ P0,
                                                   const float* __restrict__ P1,
                                                   const float* __restrict__ b,
                                                   float* __restrict__ out) {
  long i = ((long)blockIdx.x * 256 + threadIdx.x) * 4;
  int col = (int)(i & 1023);
  float4 x = *(const float4*)(X + i);
  float4 p = *(const float4*)(P0 + i);
  float4 q = *(const float4*)(P1 + i);
  float4 bb = *(const float4*)(b + col);
  float4 o;
  o.x = x.x + p.x + q.x + bb.x;
  o.y = x.y + p.y + q.y + bb.y;
  o.z = x.z + p.z + q.z + bb.z;
  o.w = x.w + p.w + q.w + bb.w;
  *(float4*)(out + i) = o;
}

// ---------------- BT GEMM: C(MxN) = alpha * A(MxK) * B(NxK)^T
// DB==3: 3-buffer counted-vmcnt pipeline (loads 2 tiles ahead, raw s_barrier,
//        never drains vmcnt to 0 in steady state). DB==2: classic dbuf+syncthreads.
// flags: 1=bias per col (bias + z*sbz), 2=relu, 4=f32 output (else bf16),
//        8 = alpha applied only to z==0 AFTER bias (for Q log2-domain pre-scale)
template <int BM, int BN, int BK, int WR, int WC, int NT, int DB>
__global__ __launch_bounds__(NT)
void gemm_bt_kernel(const u16* __restrict__ A, const u16* __restrict__ B,
                    void* __restrict__ C, const float* __restrict__ bias,
                    int lda, int ldb, int ldc, int K,
                    long sAz, long sBz, long sCz, long sbz,
                    float alpha, int flags) {
  constexpr int WTM = BM / WR, WTN = BN / WC;
  constexpr int FM = WTM / 16, FN = WTN / 16;
  constexpr int NC = BK / 8;
  __shared__ u16 lA[DB][BM * BK];
  __shared__ u16 lB[DB][BN * BK];
  const int tid = threadIdx.x, lane = tid & 63, wid = tid >> 6;
  const int wr = wid / WC, wc = wid % WC;
  const int z = blockIdx.z;

  const int nwg = gridDim.x * gridDim.y;
  const int orig = blockIdx.y * gridDim.x + blockIdx.x;
  const int qq = nwg >> 3, rr = nwg & 7;
  const int xcd = orig & 7, idx = orig >> 3;
  const int swz = (xcd < rr ? xcd * (qq + 1) : rr * (qq + 1) + (xcd - rr) * qq) + idx;
  const int bxs = swz % gridDim.x;
  const int bys = swz / gridDim.x;

  const u16* Ab = A + z * sAz + (long)bys * BM * lda;
  const u16* Bb = B + z * sBz + (long)bxs * BN * ldb;

  f32x4 acc[FM][FN] = {};

  auto stage = [&](int bufi, int k0) {
#pragma unroll
    for (int c0 = 0; c0 < BM * NC; c0 += NT) {
      int c = c0 + tid;
      if ((BM * NC) % NT == 0 || c < BM * NC) {
        int row = c / NC, ch = c % NC;
        int sch = ch ^ SWZ(BK, row);
        GLOAD16(Ab + (long)row * lda + k0 + sch * 8, &lA[bufi][c * 8]);
      }
    }
#pragma unroll
    for (int c0 = 0; c0 < BN * NC; c0 += NT) {
      int c = c0 + tid;
      if ((BN * NC) % NT == 0 || c < BN * NC) {
        int row = c / NC, ch = c % NC;
        int sch = ch ^ SWZ(BK, row);
        GLOAD16(Bb + (long)row * ldb + k0 + sch * 8, &lB[bufi][c * 8]);
      }
    }
  };

  auto compute = [&](int bufi) {
#pragma unroll
    for (int kk = 0; kk < BK / 32; kk++) {
      short8 afv[FM], bfv[FN];
#pragma unroll
      for (int i = 0; i < FM; i++) {
        int row = wr * WTM + i * 16 + (lane & 15);
        int ch = kk * 4 + (lane >> 4);
        afv[i] = *(const short8*)&lA[bufi][row * BK + ((ch ^ SWZ(BK, row)) * 8)];
      }
#pragma unroll
      for (int j = 0; j < FN; j++) {
        int row = wc * WTN + j * 16 + (lane & 15);
        int ch = kk * 4 + (lane >> 4);
        bfv[j] = *(const short8*)&lB[bufi][row * BK + ((ch ^ SWZ(BK, row)) * 8)];
      }
#pragma unroll
      for (int i = 0; i < FM; i++)
#pragma unroll
        for (int j = 0; j < FN; j++)
          acc[i][j] = __builtin_amdgcn_mfma_f32_16x16x32_bf16(afv[i], bfv[j], acc[i][j], 0, 0, 0);
    }
  };

  const int nk = K / BK;
  // per-thread loads per stage (for counted vmcnt)
  constexpr int LPS = (BM * NC) / NT + (BN * NC) / NT;
  if constexpr (DB == 3 && LPS == 2 && (BM * NC) % NT == 0 && (BN * NC) % NT == 0) {
    stage(0, 0);
    if (nk > 1) stage(1, BK);
    for (int t = 0; t < nk; t++) {
      if (t + 2 < nk) stage((t + 2) % 3, (t + 2) * BK);
      // wait until tile t's loads (oldest) are complete; keep later tiles in flight
      if (t + 2 < nk)      asm volatile("s_waitcnt vmcnt(4)" ::: "memory");
      else if (t + 1 < nk) asm volatile("s_waitcnt vmcnt(2)" ::: "memory");
      else                 asm volatile("s_waitcnt vmcnt(0)" ::: "memory");
      __builtin_amdgcn_s_barrier();          // all waves' tile-t loads landed
      __builtin_amdgcn_sched_barrier(0);
      compute(t % 3);
      __builtin_amdgcn_sched_barrier(0);
      __builtin_amdgcn_s_barrier();          // all waves done reading buf t%3
    }
  } else if constexpr (DB == 2) {
    stage(0, 0);
    __syncthreads();
    int cur = 0;
    for (int t = 0; t < nk; t++) {
      if (t + 1 < nk) stage(cur ^ 1, (t + 1) * BK);
      compute(cur);
      __syncthreads();
      cur ^= 1;
    }
  } else {
    for (int t = 0; t < nk; t++) {
      stage(0, t * BK);
      __syncthreads();
      compute(0);
      __syncthreads();
    }
  }

  const long rbase = (long)bys * BM + wr * WTM;
  const int cbase = bxs * BN + wc * WTN;
  const float* bz = bias ? (bias + z * sbz) : nullptr;
#pragma unroll
  for (int i = 0; i < FM; i++)
#pragma unroll
    for (int j = 0; j < FN; j++)
#pragma unroll
      for (int r = 0; r < 4; r++) {
        long row = rbase + i * 16 + ((lane >> 4) * 4 + r);
        int col = cbase + j * 16 + (lane & 15);
        float v = acc[i][j][r];
        if (!(flags & 8)) v *= alpha;
        if (flags & 1) v += bz[col];
        if ((flags & 8) && z == 0) v *= alpha;
        if (flags & 2) v = fmaxf(v, 0.0f);
        long off = (long)z * sCz + row * (long)ldc + col;
        if (flags & 4) ((float*)C)[off] = v;
        else ((u16*)C)[off] = f2bf(v);
      }
}

extern "C" void kernel_launch(void* const* d_in, const int* in_sizes, int n_in,
                              void* d_out, int out_size, void* d_ws, size_t ws_size,
                              hipStream_t stream) {
  const float* tgt  = (const float*)d_in[0];
  const float* mem  = (const float*)d_in[1];
  const float* pos  = (const float*)d_in[2];
  const float* qpos = (const float*)d_in[3];
  const float* wqkvS = (const float*)d_in[4];
  const float* bqkvS = (const float*)d_in[5];
  const float* woS   = (const float*)d_in[6];
  const float* boS   = (const float*)d_in[7];
  const float* wqkvC = (const float*)d_in[8];
  const float* bqkvC = (const float*)d_in[9];
  const float* woC   = (const float*)d_in[10];
  const float* boC   = (const float*)d_in[11];
  const float* w1  = (const float*)d_in[12];
  const float* b1  = (const float*)d_in[13];
  const float* w2  = (const float*)d_in[14];
  const float* b2  = (const float*)d_in[15];
  const float* g1  = (const float*)d_in[16];
  const float* be1 = (const float*)d_in[17];
  const float* g2  = (const float*)d_in[18];
  const float* be2 = (const float*)d_in[19];

  const size_t MB = 1024ull * 1024ull;
  float* out0 = (float*)d_out;
  float* wsout = out0 + 4194304;

  // ---- workspace schedule (time-shared, non-overlapping; 136MB total) ----
  char* W = (char*)d_ws;
  u16* wb = (u16*)W;
  u16* wqkvS_b = wb;
  u16* woS_b   = wb + 3145728;
  u16* wqkvC_b = wb + 4194304;
  u16* woC_b   = wb + 7340032;
  u16* w1_b    = wb + 8388608;
  u16* w2_b    = wb + 12582912;
  float* Xf   = (float*)(W + 32 * MB);
  float* OPar = (float*)(W + 48 * MB);
  u16* Pq  = (u16*)(W + 48 * MB);
  u16* bf1 = (u16*)(W + 80 * MB);
  u16* bf2 = (u16*)(W + 88 * MB);
  u16* bf3 = (u16*)(W + 96 * MB);
  float2* Ml = (float2*)(W + 96 * MB);  // 512KB; lives after QKV proj consumed bf3
  u16* Qb  = (u16*)(W + 104 * MB);
  u16* Kb  = (u16*)(W + 112 * MB);
  u16* Vtb = (u16*)(W + 120 * MB);
  u16* AOb = (u16*)(W + 128 * MB);
  u16* F1  = (u16*)(W + 104 * MB);

  // all weights -> bf16, one launch
  wcvt_kernel<<<16384, 256, 0, stream>>>(wqkvS, woS, wqkvC, woC, w1, w2, wb);

  // ================= self attention =================
  pos_embed_kernel<<<4096, 256, 0, stream>>>(tgt, qpos, bf1, bf2, bf3);
  gemm_bt_kernel<128, 128, 32, 2, 4, 512, 3><<<dim3(8, 32, 3), 512, 0, stream>>>(
      bf1, wqkvS_b, Pq, bqkvS, 1024, 1024, 3072, 1024,
      4194304, 1048576, 1024, 1024, QSCALE, 1 | 8);
  split_qkv_kernel<<<6144, 256, 0, stream>>>(Pq, Qb, Kb, Vtb);
  fattn_kernel<<<dim3(16, 64), 256, 0, stream>>>(Qb, Kb, Vtb, AOb, nullptr);
  gemm_bt_kernel<128, 128, 32, 2, 4, 512, 3><<<dim3(8, 32, 2), 512, 0, stream>>>(
      AOb, woS_b, OPar, nullptr, 1024, 1024, 1024, 512,
      512, 512, 4194304, 0, 1.0f, 4);
  ln_kernel<<<4096, 256, 0, stream>>>(tgt, OPar, OPar + 4194304, boS, g1, be1, Xf, nullptr);

  // ================= cross attention =================
  pos_embed_kernel<<<4096, 256, 0, stream>>>(Xf, qpos, bf1, nullptr, nullptr);
  pos_embed_kernel<<<4096, 256, 0, stream>>>(mem, pos, bf2, nullptr, bf3);
  gemm_bt_kernel<128, 128, 32, 2, 4, 512, 3><<<dim3(8, 32, 3), 512, 0, stream>>>(
      bf1, wqkvC_b, Pq, bqkvC, 1024, 1024, 3072, 1024,
      4194304, 1048576, 1024, 1024, QSCALE, 1 | 8);
  split_qkv_kernel<<<6144, 256, 0, stream>>>(Pq, Qb, Kb, Vtb);
  fattn_kernel<<<dim3(16, 64), 256, 0, stream>>>(Qb, Kb, Vtb, AOb, Ml);
  wsrec_kernel<<<dim3(16, 16, 4), 256, 0, stream>>>(Qb, Kb, Ml, wsout);
  gemm_bt_kernel<128, 128, 32, 2, 4, 512, 3><<<dim3(8, 32, 2), 512, 0, stream>>>(
      AOb, woC_b, OPar, nullptr, 1024, 1024, 1024, 512,
      512, 512, 4194304, 0, 1.0f, 4);
  ln_kernel<<<4096, 256, 0, stream>>>(Xf, OPar, OPar + 4194304, boC, g2, be2, Xf, bf1);

  // ================= FFN =================
  gemm_bt_kernel<128, 128, 32, 2, 4, 512, 3><<<dim3(32, 32, 1), 512, 0, stream>>>(
      bf1, w1_b, F1, b1, 1024, 1024, 4096, 1024, 0, 0, 0, 0, 1.0f, 1 | 2);
  gemm_bt_kernel<128, 128, 32, 2, 4, 512, 3><<<dim3(8, 32, 2), 512, 0, stream>>>(
      F1, w2_b, OPar, nullptr, 4096, 4096, 1024, 2048,
      2048, 2048, 4194304, 0, 1.0f, 4);
  add3_kernel<<<4096, 256, 0, stream>>>(Xf, OPar, OPar + 4194304, b2, out0);
}

// Round 11
// 403.213 us; speedup vs baseline: 1.1602x; 1.1095x over previous
//
#include <hip/hip_runtime.h>

typedef unsigned short u16;
typedef __attribute__((ext_vector_type(8))) short short8;
typedef __attribute__((ext_vector_type(8))) unsigned short u16x8;
typedef __attribute__((ext_vector_type(4))) float f32x4;

#define GLOAD16(SRC, DST) __builtin_amdgcn_global_load_lds( \
    (const __attribute__((address_space(1))) void*)(SRC),   \
    (__attribute__((address_space(3))) void*)(DST), 16, 0, 0)

// LDS chunk swizzle: spreads a column of 16B chunks across bank-groups.
#define SWZ(BKv, r) ((BKv) == 32 ? (((r) >> 1) & 3) : ((r) & 7))

// 0.125 * log2(e): folds softmax scale + exp->exp2 conversion into Q projection
#define QSCALE 0.18033688011112042f

__device__ __forceinline__ u16 f2bf(float f) {
  union { float f; unsigned u; } v; v.f = f;
  unsigned r = v.u + 0x7fffu + ((v.u >> 16) & 1u);
  return (u16)(r >> 16);
}
__device__ __forceinline__ float bf2f(u16 h) {
  union { unsigned u; float f; } v; v.u = ((unsigned)h) << 16;
  return v.f;
}

// ---------------- fused weights f32 -> bf16 convert (6 segments, contiguous dst) ----
__global__ __launch_bounds__(256) void wcvt_kernel(const float* __restrict__ s0,
                                                   const float* __restrict__ s1,
                                                   const float* __restrict__ s2,
                                                   const float* __restrict__ s3,
                                                   const float* __restrict__ s4,
                                                   const float* __restrict__ s5,
                                                   u16* __restrict__ dst) {
  long i = ((long)blockIdx.x * 256 + threadIdx.x) * 4;
  const float* src; long off;
  if (i < 3145728)        { src = s0; off = 0; }
  else if (i < 4194304)   { src = s1; off = 3145728; }
  else if (i < 7340032)   { src = s2; off = 4194304; }
  else if (i < 8388608)   { src = s3; off = 7340032; }
  else if (i < 12582912)  { src = s4; off = 8388608; }
  else                    { src = s5; off = 12582912; }
  float4 v = *(const float4*)(src + (i - off));
  ushort4 o; o.x = f2bf(v.x); o.y = f2bf(v.y); o.z = f2bf(v.z); o.w = f2bf(v.w);
  *(ushort4*)(dst + i) = o;
}

// ---------------- pos embed (revolution-domain v_sin/v_cos) + optional raw cast ----
__global__ __launch_bounds__(256) void pos_embed_kernel(const float* __restrict__ x,
                                                        const float* __restrict__ pos,
                                                        u16* __restrict__ out,
                                                        u16* __restrict__ out2,
                                                        u16* __restrict__ raw) {
  int m = blockIdx.x;
  int tid = threadIdx.x;
  float p = pos[m];
  long base = ((long)m << 10);
  int j = tid * 4;
  float4 xv = *(const float4*)(x + base + j);
  const float inv = 1.0f / 2048.0f;  // (pi/1024) / (2*pi)
  float r0 = p * (float)(j + 0) * inv;
  float r1 = p * (float)(j + 1) * inv;
  float r2 = p * (float)(j + 2) * inv;
  float r3 = p * (float)(j + 3) * inv;
  float s1 = __builtin_amdgcn_sinf(r0 - floorf(r0));
  float c0 = __builtin_amdgcn_cosf(r1 - floorf(r1));
  float s3 = __builtin_amdgcn_sinf(r2 - floorf(r2));
  float c2 = __builtin_amdgcn_cosf(r3 - floorf(r3));
  ushort4 o;
  o.x = f2bf(c0 * xv.y);
  o.y = f2bf(s1 * xv.x);
  o.z = f2bf(c2 * xv.w);
  o.w = f2bf(s3 * xv.z);
  *(ushort4*)(out + base + j) = o;
  if (out2) *(ushort4*)(out2 + base + j) = o;
  if (raw) {
    ushort4 rw; rw.x = f2bf(xv.x); rw.y = f2bf(xv.y); rw.z = f2bf(xv.z); rw.w = f2bf(xv.w);
    *(ushort4*)(raw + base + j) = rw;
  }
}

// ---------------- flash attention: staged K/V, swapped QK^T, exp2 + defer-max ------
__global__ __launch_bounds__(256) void fattn_kernel(const u16* __restrict__ Q,
                                                    const u16* __restrict__ K,
                                                    const u16* __restrict__ Vt,
                                                    u16* __restrict__ AO,
                                                    float2* __restrict__ Ml) {
  __shared__ u16 lK[2][4096];
  __shared__ u16 lV[2][4096];
  __shared__ u16 lP[4][1024];
  const int tid = threadIdx.x, lane = tid & 63, wid = tid >> 6;
  const int nb = gridDim.x * gridDim.y;
  const int orig = blockIdx.y * gridDim.x + blockIdx.x;
  const int swz = (orig & 7) * (nb >> 3) + (orig >> 3);
  const int qt = swz & 15;
  const int bh = swz >> 4;
  const int b = bh >> 4, h = bh & 15;
  const u16* Qp = Q + ((long)bh << 16);
  const u16* Kp = K + ((long)bh << 16);
  const u16* Vp = Vt + ((long)bh << 16);
  const int q0 = qt << 6;
  const int cr = lane >> 4;

  short8 af0, af1;  // Q fragment (B-operand): row = lane&15 = q-row within wave block
  {
    const u16* qs = Qp + (long)(q0 + wid * 16 + (lane & 15)) * 64 + cr * 8;
    af0 = *(const short8*)qs;
    af1 = *(const short8*)(qs + 32);
  }

  float m = -1e30f, l = 0.f;  // per-lane scalar: softmax state of q = lane&15
  f32x4 acco[4] = {};

  auto stage = [&](int bufi, int kv) {
    int s0 = kv << 6;
#pragma unroll
    for (int it = 0; it < 2; it++) {
      int c = it * 256 + tid;
      int row = c >> 3, ch = c & 7;
      int sch = (ch ^ (row & 7)) * 8;  // pre-swizzled source, linear LDS dst
      GLOAD16(Kp + (long)(s0 + row) * 64 + sch, &lK[bufi][c * 8]);
      GLOAD16(Vp + (long)row * 1024 + s0 + sch, &lV[bufi][c * 8]);
    }
  };

  stage(0, 0);
  __syncthreads();
  int buf = 0;
  for (int kv = 0; kv < 16; kv++) {
    if (kv < 15) stage(buf ^ 1, kv + 1);
    // S^T tile: accs[j][r] = S[q=lane&15][kv = j*16 + cr*4 + r]
    f32x4 accs[4];
    __builtin_amdgcn_s_setprio(1);
#pragma unroll
    for (int j = 0; j < 4; j++) {
      int sr = j * 16 + (lane & 15);
      const short8 kf0 = *(const short8*)&lK[buf][sr * 64 + ((cr ^ (sr & 7)) * 8)];
      const short8 kf1 = *(const short8*)&lK[buf][sr * 64 + (((4 + cr) ^ (sr & 7)) * 8)];
      f32x4 zz = {};
      zz = __builtin_amdgcn_mfma_f32_16x16x32_bf16(kf0, af0, zz, 0, 0, 0);
      accs[j] = __builtin_amdgcn_mfma_f32_16x16x32_bf16(kf1, af1, zz, 0, 0, 0);
    }
    __builtin_amdgcn_s_setprio(0);
    // row max: 15 local fmax + 2 shfl stages (partners lane^16, lane^32)
    float tm = fmaxf(fmaxf(fmaxf(accs[0][0], accs[0][1]), fmaxf(accs[0][2], accs[0][3])),
                     fmaxf(fmaxf(accs[1][0], accs[1][1]), fmaxf(accs[1][2], accs[1][3])));
    float tm2 = fmaxf(fmaxf(fmaxf(accs[2][0], accs[2][1]), fmaxf(accs[2][2], accs[2][3])),
                      fmaxf(fmaxf(accs[3][0], accs[3][1]), fmaxf(accs[3][2], accs[3][3])));
    tm = fmaxf(tm, tm2);
    tm = fmaxf(tm, __shfl_xor(tm, 16));
    tm = fmaxf(tm, __shfl_xor(tm, 32));
    // defer-max: rescale only when max grew by > 8 (P bounded by 2^8)
    if (!__all(tm - m <= 8.0f)) {
      float mn = fmaxf(m, tm);
      float f = __builtin_amdgcn_exp2f(m - mn);
      m = mn; l *= f;
#pragma unroll
      for (int r = 0; r < 4; r++) {
        float fr = __shfl(f, cr * 4 + r);
        acco[0][r] *= fr; acco[1][r] *= fr; acco[2][r] *= fr; acco[3][r] *= fr;
      }
    }
    float rs = 0.f;
#pragma unroll
    for (int j = 0; j < 4; j++)
#pragma unroll
      for (int r = 0; r < 4; r++) {
        float p = __builtin_amdgcn_exp2f(accs[j][r] - m);
        accs[j][r] = p;
        rs += p;
      }
    rs += __shfl_xor(rs, 16);
    rs += __shfl_xor(rs, 32);
    l += rs;
    // P -> wave-private swizzled LDS: lane writes row q=lane&15, kv=j*16+cr*4+{0..3}
    {
      u16* pw = lP[wid];
      int q = lane & 15;
      int rowoff = q * 64;
      int qs7 = q & 7;
#pragma unroll
      for (int j = 0; j < 4; j++) {
        uint2 pk;
        asm("v_cvt_pk_bf16_f32 %0, %1, %2"
            : "=v"(pk.x) : "v"(accs[j][0]), "v"(accs[j][1]));
        asm("v_cvt_pk_bf16_f32 %0, %1, %2"
            : "=v"(pk.y) : "v"(accs[j][2]), "v"(accs[j][3]));
        int chunk = 2 * j + (cr >> 1);
        int idx = rowoff + ((chunk ^ qs7) * 8) + 4 * (cr & 1);
        *(uint2*)(pw + idx) = pk;
      }
    }
    // PV accumulate (compiler inserts the lgkmcnt wait for the LDS dep)
    {
      int ql = lane & 15;
      const u16* pr = &lP[wid][ql * 64];
      short8 pa0 = *(const short8*)&pr[(cr ^ (ql & 7)) * 8];
      short8 pa1 = *(const short8*)&pr[((4 + cr) ^ (ql & 7)) * 8];
      __builtin_amdgcn_s_setprio(1);
#pragma unroll
      for (int j = 0; j < 4; j++) {
        int dr = j * 16 + (lane & 15);
        const short8 vf0 = *(const short8*)&lV[buf][dr * 64 + ((cr ^ (dr & 7)) * 8)];
        const short8 vf1 = *(const short8*)&lV[buf][dr * 64 + (((4 + cr) ^ (dr & 7)) * 8)];
        acco[j] = __builtin_amdgcn_mfma_f32_16x16x32_bf16(pa0, vf0, acco[j], 0, 0, 0);
        acco[j] = __builtin_amdgcn_mfma_f32_16x16x32_bf16(pa1, vf1, acco[j], 0, 0, 0);
      }
      __builtin_amdgcn_s_setprio(0);
    }
    __syncthreads();
    buf ^= 1;
  }
  float invl = 1.0f / l;
  float ilr[4];
#pragma unroll
  for (int r = 0; r < 4; r++) ilr[r] = __shfl(invl, cr * 4 + r);
#pragma unroll
  for (int j = 0; j < 4; j++)
#pragma unroll
    for (int r = 0; r < 4; r++) {
      int t = q0 + wid * 16 + cr * 4 + r;
      int e = (b << 10) + (h << 6) + j * 16 + (lane & 15);
      AO[(long)t * 4096 + e] = f2bf(acco[j][r] * ilr[r]);
    }
  if (Ml && lane < 16) {
    int t = q0 + wid * 16 + lane;
    Ml[((long)bh << 10) + t] = make_float2(m, invl);
  }
}

// ---------------- ws recompute: ws[b][l][s] = 1/16 sum_h exp2(S'-m)*invl ----------
__global__ __launch_bounds__(256) void wsrec_kernel(const u16* __restrict__ Q,
                                                    const u16* __restrict__ K,
                                                    const float2* __restrict__ Ml,
                                                    float* __restrict__ ws) {
  __shared__ u16 lK[2][4096];
  const int tid = threadIdx.x, lane = tid & 63, wid = tid >> 6;
  const int nb = gridDim.x * gridDim.y;  // 256
  const int orig = blockIdx.y * gridDim.x + blockIdx.x;
  const int swz = (orig & 7) * (nb >> 3) + (orig >> 3);
  const int st = swz & 15, lt = swz >> 4;
  const int b = blockIdx.z;
  const int s0 = st << 6, l0 = lt << 6;
  const int cr = lane >> 4;

  auto stage = [&](int bufi, int h) {
    const u16* Kp = K + (((long)(b * 16 + h)) << 16);
#pragma unroll
    for (int it = 0; it < 2; it++) {
      int c = it * 256 + tid;
      int row = c >> 3, ch = c & 7;
      GLOAD16(Kp + (long)(s0 + row) * 64 + ((ch ^ (row & 7)) * 8), &lK[bufi][c * 8]);
    }
  };

  f32x4 wacc[4] = {};
  stage(0, 0);
  __syncthreads();
  int buf = 0;
  for (int h = 0; h < 16; h++) {
    if (h < 15) stage(buf ^ 1, h + 1);
    const int bh = b * 16 + h;
    short8 af0, af1;
    {
      const u16* qs = Q + ((long)bh << 16) + (long)(l0 + wid * 16 + (lane & 15)) * 64 + cr * 8;
      af0 = *(const short8*)qs;
      af1 = *(const short8*)(qs + 32);
    }
    f32x4 accs[4];
    __builtin_amdgcn_s_setprio(1);
#pragma unroll
    for (int j = 0; j < 4; j++) {
      int sr = j * 16 + (lane & 15);
      const short8 kf0 = *(const short8*)&lK[buf][sr * 64 + ((cr ^ (sr & 7)) * 8)];
      const short8 kf1 = *(const short8*)&lK[buf][sr * 64 + (((4 + cr) ^ (sr & 7)) * 8)];
      f32x4 zz = {};
      zz = __builtin_amdgcn_mfma_f32_16x16x32_bf16(af0, kf0, zz, 0, 0, 0);
      accs[j] = __builtin_amdgcn_mfma_f32_16x16x32_bf16(af1, kf1, zz, 0, 0, 0);
    }
    __builtin_amdgcn_s_setprio(0);
    float mm[4], il[4];
#pragma unroll
    for (int r = 0; r < 4; r++) {
      float2 v = Ml[((long)bh << 10) + l0 + wid * 16 + (lane >> 4) * 4 + r];
      mm[r] = v.x; il[r] = v.y * 0.0625f;
    }
#pragma unroll
    for (int j = 0; j < 4; j++)
#pragma unroll
      for (int r = 0; r < 4; r++)
        wacc[j][r] += __builtin_amdgcn_exp2f(accs[j][r] - mm[r]) * il[r];
    __syncthreads();
    buf ^= 1;
  }
#pragma unroll
  for (int j = 0; j < 4; j++)
#pragma unroll
    for (int r = 0; r < 4; r++) {
      int li = l0 + wid * 16 + (lane >> 4) * 4 + r;
      int si = s0 + j * 16 + (lane & 15);
      ws[((long)b << 20) + (long)li * 1024 + si] = wacc[j][r];
    }
}

// ---------------- layernorm (ddof=1): x = X + D1 [+ D2] [+ bo]; LN(x) ------------
// If bfout && pepos: bfout = pos_embed(LN(x)) (bf16). Else bfout = bf16(LN(x)).
__global__ __launch_bounds__(256) void ln_kernel(const float* __restrict__ X,
                                                 const float* __restrict__ D1,
                                                 const float* __restrict__ D2,
                                                 const float* __restrict__ bo,
                                                 const float* __restrict__ g,
                                                 const float* __restrict__ be,
                                                 float* __restrict__ out,
                                                 u16* __restrict__ bfout,
                                                 const float* __restrict__ pepos) {
  int mrow = blockIdx.x;
  int tid = threadIdx.x, lane = tid & 63, wid = tid >> 6;
  long base = ((long)mrow << 10);
  float4 a = *(const float4*)(X + base + tid * 4);
  float4 b = *(const float4*)(D1 + base + tid * 4);
  float x0 = a.x + b.x, x1 = a.y + b.y, x2 = a.z + b.z, x3 = a.w + b.w;
  if (D2) {
    float4 c = *(const float4*)(D2 + base + tid * 4);
    x0 += c.x; x1 += c.y; x2 += c.z; x3 += c.w;
  }
  if (bo) {
    float4 c = *(const float4*)(bo + tid * 4);
    x0 += c.x; x1 += c.y; x2 += c.z; x3 += c.w;
  }
  float s = x0 + x1 + x2 + x3;
#pragma unroll
  for (int o = 32; o; o >>= 1) s += __shfl_xor(s, o);
  __shared__ float red[4];
  if (lane == 0) red[wid] = s;
  __syncthreads();
  float mean = (red[0] + red[1] + red[2] + red[3]) * (1.0f / 1024.0f);
  float d0 = x0 - mean, d1 = x1 - mean, d2 = x2 - mean, d3 = x3 - mean;
  float ss = d0 * d0 + d1 * d1 + d2 * d2 + d3 * d3;
#pragma unroll
  for (int o = 32; o; o >>= 1) ss += __shfl_xor(ss, o);
  __syncthreads();
  if (lane == 0) red[wid] = ss;
  __syncthreads();
  float var = (red[0] + red[1] + red[2] + red[3]) * (1.0f / 1023.0f);
  float sc = 1.0f / sqrtf(var + 1e-5f);
  float4 gv = *(const float4*)(g + tid * 4);
  float4 bv = *(const float4*)(be + tid * 4);
  float y0 = gv.x * d0 * sc + bv.x;
  float y1 = gv.y * d1 * sc + bv.y;
  float y2 = gv.z * d2 * sc + bv.z;
  float y3 = gv.w * d3 * sc + bv.w;
  float4 o4; o4.x = y0; o4.y = y1; o4.z = y2; o4.w = y3;
  *(float4*)(out + base + tid * 4) = o4;
  if (bfout) {
    ushort4 hh;
    if (pepos) {
      float p = pepos[mrow];
      int j = tid * 4;
      const float inv = 1.0f / 2048.0f;
      float r0 = p * (float)(j + 0) * inv;
      float r1 = p * (float)(j + 1) * inv;
      float r2 = p * (float)(j + 2) * inv;
      float r3 = p * (float)(j + 3) * inv;
      float s1 = __builtin_amdgcn_sinf(r0 - floorf(r0));
      float c0 = __builtin_amdgcn_cosf(r1 - floorf(r1));
      float s3 = __builtin_amdgcn_sinf(r2 - floorf(r2));
      float c2 = __builtin_amdgcn_cosf(r3 - floorf(r3));
      hh.x = f2bf(c0 * y1);
      hh.y = f2bf(s1 * y0);
      hh.z = f2bf(c2 * y3);
      hh.w = f2bf(s3 * y2);
    } else {
      hh.x = f2bf(y0); hh.y = f2bf(y1); hh.z = f2bf(y2); hh.w = f2bf(y3);
    }
    *(ushort4*)(bfout + base + tid * 4) = hh;
  }
}

// ---------------- out = X + P0 + P1 + b[col] ----------------
__global__ __launch_bounds__(256) void add3_kernel(const float* __restrict__ X,
                                                   const float* __restrict__ P0,
                                                   const float* __restrict__ P1,
                                                   const float* __restrict__ b,
                                                   float* __restrict__ out) {
  long i = ((long)blockIdx.x * 256 + threadIdx.x) * 4;
  int col = (int)(i & 1023);
  float4 x = *(const float4*)(X + i);
  float4 p = *(const float4*)(P0 + i);
  float4 q = *(const float4*)(P1 + i);
  float4 bb = *(const float4*)(b + col);
  float4 o;
  o.x = x.x + p.x + q.x + bb.x;
  o.y = x.y + p.y + q.y + bb.y;
  o.z = x.z + p.z + q.z + bb.z;
  o.w = x.w + p.w + q.w + bb.w;
  *(float4*)(out + i) = o;
}

// ---------------- BT GEMM: C(MxN) = alpha * A(MxK) * B(NxK)^T  (2-phase dbuf)
// flags: 1=bias per col (bias + z*sbz), 2=relu, 4=f32 output (else bf16),
//        8=alpha applied only to z==0 AFTER bias (Q log2-domain pre-scale),
//        16=QKV scatter epilogue: z selects Q/K/V; C = Qb base
//           (Kb = C+4194304, Vtb = C+8388608); row->(t,b), col->(h,d).
template <int BM, int BN, int BK, int WR, int WC, int NT, int DB>
__global__ __launch_bounds__(NT)
void gemm_bt_kernel(const u16* __restrict__ A, const u16* __restrict__ B,
                    void* __restrict__ C, const float* __restrict__ bias,
                    int lda, int ldb, int ldc, int K,
                    long sAz, long sBz, long sCz, long sbz,
                    float alpha, int flags) {
  constexpr int WTM = BM / WR, WTN = BN / WC;
  constexpr int FM = WTM / 16, FN = WTN / 16;
  constexpr int NC = BK / 8;
  __shared__ u16 lA[DB][BM * BK];
  __shared__ u16 lB[DB][BN * BK];
  const int tid = threadIdx.x, lane = tid & 63, wid = tid >> 6;
  const int wr = wid / WC, wc = wid % WC;
  const int z = blockIdx.z;

  const int nwg = gridDim.x * gridDim.y;
  const int orig = blockIdx.y * gridDim.x + blockIdx.x;
  const int qq = nwg >> 3, rr = nwg & 7;
  const int xcd = orig & 7, idx = orig >> 3;
  const int swz = (xcd < rr ? xcd * (qq + 1) : rr * (qq + 1) + (xcd - rr) * qq) + idx;
  const int bxs = swz % gridDim.x;
  const int bys = swz / gridDim.x;

  const u16* Ab = A + z * sAz + (long)bys * BM * lda;
  const u16* Bb = B + z * sBz + (long)bxs * BN * ldb;

  f32x4 acc[FM][FN] = {};

  auto stage = [&](int bufi, int k0) {
#pragma unroll
    for (int c0 = 0; c0 < BM * NC; c0 += NT) {
      int c = c0 + tid;
      if ((BM * NC) % NT == 0 || c < BM * NC) {
        int row = c / NC, ch = c % NC;
        int sch = ch ^ SWZ(BK, row);
        GLOAD16(Ab + (long)row * lda + k0 + sch * 8, &lA[bufi][c * 8]);
      }
    }
#pragma unroll
    for (int c0 = 0; c0 < BN * NC; c0 += NT) {
      int c = c0 + tid;
      if ((BN * NC) % NT == 0 || c < BN * NC) {
        int row = c / NC, ch = c % NC;
        int sch = ch ^ SWZ(BK, row);
        GLOAD16(Bb + (long)row * ldb + k0 + sch * 8, &lB[bufi][c * 8]);
      }
    }
  };

  auto compute = [&](int bufi) {
#pragma unroll
    for (int kk = 0; kk < BK / 32; kk++) {
      short8 afv[FM], bfv[FN];
#pragma unroll
      for (int i = 0; i < FM; i++) {
        int row = wr * WTM + i * 16 + (lane & 15);
        int ch = kk * 4 + (lane >> 4);
        afv[i] = *(const short8*)&lA[bufi][row * BK + ((ch ^ SWZ(BK, row)) * 8)];
      }
#pragma unroll
      for (int j = 0; j < FN; j++) {
        int row = wc * WTN + j * 16 + (lane & 15);
        int ch = kk * 4 + (lane >> 4);
        bfv[j] = *(const short8*)&lB[bufi][row * BK + ((ch ^ SWZ(BK, row)) * 8)];
      }
#pragma unroll
      for (int i = 0; i < FM; i++)
#pragma unroll
        for (int j = 0; j < FN; j++)
          acc[i][j] = __builtin_amdgcn_mfma_f32_16x16x32_bf16(afv[i], bfv[j], acc[i][j], 0, 0, 0);
    }
  };

  const int nk = K / BK;
  if constexpr (DB == 2) {
    stage(0, 0);
    __syncthreads();
    int cur = 0;
    for (int t = 0; t < nk; t++) {
      if (t + 1 < nk) stage(cur ^ 1, (t + 1) * BK);
      compute(cur);
      __syncthreads();
      cur ^= 1;
    }
  } else {
    for (int t = 0; t < nk; t++) {
      stage(0, t * BK);
      __syncthreads();
      compute(0);
      __syncthreads();
    }
  }

  const long rbase = (long)bys * BM + wr * WTM;
  const int cbase = bxs * BN + wc * WTN;
  const float* bz = bias ? (bias + z * sbz) : nullptr;
#pragma unroll
  for (int i = 0; i < FM; i++)
#pragma unroll
    for (int j = 0; j < FN; j++)
#pragma unroll
      for (int r = 0; r < 4; r++) {
        long row = rbase + i * 16 + ((lane >> 4) * 4 + r);
        int col = cbase + j * 16 + (lane & 15);
        float v = acc[i][j][r];
        if (!(flags & 8)) v *= alpha;
        if (flags & 1) v += bz[col];
        if ((flags & 8) && z == 0) v *= alpha;
        if (flags & 2) v = fmaxf(v, 0.0f);
        if (flags & 16) {
          int t = (int)(row >> 2), bb = (int)(row & 3);
          int hh = col >> 6, dd = col & 63;
          long base16 = ((long)(bb * 16 + hh)) << 16;
          long off = (long)z * 4194304 + base16 +
                     (z == 2 ? (long)dd * 1024 + t : (long)t * 64 + dd);
          ((u16*)C)[off] = f2bf(v);
        } else {
          long off = (long)z * sCz + row * (long)ldc + col;
          if (flags & 4) ((float*)C)[off] = v;
          else ((u16*)C)[off] = f2bf(v);
        }
      }
}

extern "C" void kernel_launch(void* const* d_in, const int* in_sizes, int n_in,
                              void* d_out, int out_size, void* d_ws, size_t ws_size,
                              hipStream_t stream) {
  const float* tgt  = (const float*)d_in[0];
  const float* mem  = (const float*)d_in[1];
  const float* pos  = (const float*)d_in[2];
  const float* qpos = (const float*)d_in[3];
  const float* wqkvS = (const float*)d_in[4];
  const float* bqkvS = (const float*)d_in[5];
  const float* woS   = (const float*)d_in[6];
  const float* boS   = (const float*)d_in[7];
  const float* wqkvC = (const float*)d_in[8];
  const float* bqkvC = (const float*)d_in[9];
  const float* woC   = (const float*)d_in[10];
  const float* boC   = (const float*)d_in[11];
  const float* w1  = (const float*)d_in[12];
  const float* b1  = (const float*)d_in[13];
  const float* w2  = (const float*)d_in[14];
  const float* b2  = (const float*)d_in[15];
  const float* g1  = (const float*)d_in[16];
  const float* be1 = (const float*)d_in[17];
  const float* g2  = (const float*)d_in[18];
  const float* be2 = (const float*)d_in[19];

  const size_t MB = 1024ull * 1024ull;
  float* out0 = (float*)d_out;
  float* wsout = out0 + 4194304;

  // ---- workspace schedule (time-shared, non-overlapping; 136MB total) ----
  char* W = (char*)d_ws;
  u16* wb = (u16*)W;
  u16* wqkvS_b = wb;
  u16* woS_b   = wb + 3145728;
  u16* wqkvC_b = wb + 4194304;
  u16* woC_b   = wb + 7340032;
  u16* w1_b    = wb + 8388608;
  u16* w2_b    = wb + 12582912;
  float* Xf   = (float*)(W + 32 * MB);
  float* OPar = (float*)(W + 48 * MB);
  u16* bf1 = (u16*)(W + 80 * MB);
  u16* bf2 = (u16*)(W + 88 * MB);
  u16* bf3 = (u16*)(W + 96 * MB);
  float2* Ml = (float2*)(W + 96 * MB);  // 512KB; lives after QKV proj consumed bf3
  u16* Qb  = (u16*)(W + 104 * MB);      // Kb = Qb+4M elems, Vtb = Qb+8M elems
  u16* Kb  = (u16*)(W + 112 * MB);
  u16* Vtb = (u16*)(W + 120 * MB);
  u16* AOb = (u16*)(W + 128 * MB);
  u16* F1  = (u16*)(W + 104 * MB);

  // all weights -> bf16, one launch
  wcvt_kernel<<<16384, 256, 0, stream>>>(wqkvS, woS, wqkvC, woC, w1, w2, wb);

  // ================= self attention =================
  pos_embed_kernel<<<4096, 256, 0, stream>>>(tgt, qpos, bf1, bf2, bf3);
  // QKV z-batched, scatter epilogue straight into Qb/Kb/Vtb
  gemm_bt_kernel<128, 128, 32, 2, 4, 512, 2><<<dim3(8, 32, 3), 512, 0, stream>>>(
      bf1, wqkvS_b, Qb, bqkvS, 1024, 1024, 0, 1024,
      4194304, 1048576, 0, 1024, QSCALE, 1 | 8 | 16);
  fattn_kernel<<<dim3(16, 64), 256, 0, stream>>>(Qb, Kb, Vtb, AOb, nullptr);
  gemm_bt_kernel<128, 128, 32, 2, 4, 512, 2><<<dim3(8, 32, 2), 512, 0, stream>>>(
      AOb, woS_b, OPar, nullptr, 1024, 1024, 1024, 512,
      512, 512, 4194304, 0, 1.0f, 4);
  // LN1 + fused pos-embed for cross-attention Q (bf1)
  ln_kernel<<<4096, 256, 0, stream>>>(tgt, OPar, OPar + 4194304, boS, g1, be1,
                                      Xf, bf1, qpos);

  // ================= cross attention =================
  pos_embed_kernel<<<4096, 256, 0, stream>>>(mem, pos, bf2, nullptr, bf3);
  gemm_bt_kernel<128, 128, 32, 2, 4, 512, 2><<<dim3(8, 32, 3), 512, 0, stream>>>(
      bf1, wqkvC_b, Qb, bqkvC, 1024, 1024, 0, 1024,
      4194304, 1048576, 0, 1024, QSCALE, 1 | 8 | 16);
  fattn_kernel<<<dim3(16, 64), 256, 0, stream>>>(Qb, Kb, Vtb, AOb, Ml);
  wsrec_kernel<<<dim3(16, 16, 4), 256, 0, stream>>>(Qb, Kb, Ml, wsout);
  gemm_bt_kernel<128, 128, 32, 2, 4, 512, 2><<<dim3(8, 32, 2), 512, 0, stream>>>(
      AOb, woC_b, OPar, nullptr, 1024, 1024, 1024, 512,
      512, 512, 4194304, 0, 1.0f, 4);
  ln_kernel<<<4096, 256, 0, stream>>>(Xf, OPar, OPar + 4194304, boC, g2, be2,
                                      Xf, bf1, nullptr);

  // ================= FFN =================
  gemm_bt_kernel<128, 128, 32, 2, 4, 512, 2><<<dim3(32, 32, 1), 512, 0, stream>>>(
      bf1, w1_b, F1, b1, 1024, 1024, 4096, 1024, 0, 0, 0, 0, 1.0f, 1 | 2);
  gemm_bt_kernel<128, 128, 32, 2, 4, 512, 2><<<dim3(8, 32, 2), 512, 0, stream>>>(
      F1, w2_b, OPar, nullptr, 4096, 4096, 1024, 2048,
      2048, 2048, 4194304, 0, 1.0f, 4);
  add3_kernel<<<4096, 256, 0, stream>>>(Xf, OPar, OPar + 4194304, b2, out0);
}